// Round 4
// baseline (309.485 us; speedup 1.0000x reference)
//
#include <hip/hip_runtime.h>
#include <stdint.h>

#define NB 4
#define NT 2048
#define ND 1024
#define NH 16
#define NDK 64
#define NTD 3072   // 3*ND

typedef __attribute__((ext_vector_type(8))) short short8;
typedef __attribute__((ext_vector_type(4))) float f32x4;
typedef unsigned short u16;
typedef unsigned int u32;

__device__ __forceinline__ u16 f2bf(float f) {
    u32 u = __builtin_bit_cast(u32, f);
    u += 0x7fffu + ((u >> 16) & 1u);   // RNE
    return (u16)(u >> 16);
}
__device__ __forceinline__ float bf2f(u16 s) {
    u32 u = ((u32)s) << 16;
    return __builtin_bit_cast(float, u);
}

__device__ __forceinline__ void gl_lds16(const u16* g, u16* l) {
    __builtin_amdgcn_global_load_lds(
        (const __attribute__((address_space(1))) u32*)g,
        (__attribute__((address_space(3))) u32*)l, 16, 0, 0);
}

// XOR-swizzled tile index (rows of 32 u16 / 64B, 4 atoms of 8 u16).
__device__ __forceinline__ int swz(int row, int col) {
    return row * 32 + ((((col >> 3) ^ (row >> 1) ^ (row >> 3)) & 3) << 3) + (col & 7);
}

// ---------------- fused fp32 -> bf16 (RNE) for x, W_qkv, W_o ----------------
__global__ __launch_bounds__(256) void cvt_all(const float* __restrict__ x,
                                               const float* __restrict__ wqkv,
                                               const float* __restrict__ wo,
                                               u16* __restrict__ xb,
                                               u16* __restrict__ wqb,
                                               u16* __restrict__ wob) {
    const int n0 = NB * NT * ND;       // 8388608
    const int n1 = 3 * ND * ND;        // 3145728
    int i = (blockIdx.x * 256 + threadIdx.x) * 8;
    const float* src;
    u16* dst;
    if (i < n0) {
        src = x + i; dst = xb + i;
    } else if (i < n0 + n1) {
        src = wqkv + (i - n0); dst = wqb + (i - n0);
    } else {
        src = wo + (i - n0 - n1); dst = wob + (i - n0 - n1);
    }
    float4 a = *(const float4*)(src);
    float4 b = *(const float4*)(src + 4);
    short8 r;
    r[0] = (short)f2bf(a.x); r[1] = (short)f2bf(a.y);
    r[2] = (short)f2bf(a.z); r[3] = (short)f2bf(a.w);
    r[4] = (short)f2bf(b.x); r[5] = (short)f2bf(b.y);
    r[6] = (short)f2bf(b.z); r[7] = (short)f2bf(b.w);
    *(short8*)(dst) = r;
}

// ---------------- bf16 GEMM: C[M,N] = A[M,K] * Bm[N,K]^T ----------------
// T3-minimum prefetch: stage tile k+1 into buf^1 BEFORE computing tile k,
// single barrier per K-step (vmcnt(0)-drain covered by the MFMA phase).
// XCD-slab fid swizzle retained (bijective, correctness-safe).
template <typename OutT>
__global__ __launch_bounds__(256) void gemm_bt(const u16* __restrict__ A,
                                               const u16* __restrict__ Bm,
                                               OutT* __restrict__ C,
                                               int M, int N, int K) {
    __shared__ __align__(16) u16 As[2][128 * 32];
    __shared__ __align__(16) u16 Bs[2][128 * 32];
    const int tid  = threadIdx.x;
    const int wave = tid >> 6, lane = tid & 63;
    const int quad = lane >> 4, l16 = lane & 15;
    const int wm = wave >> 1, wn = wave & 1;
    const int fid = blockIdx.y * gridDim.x + blockIdx.x;   // gridDim.x == 64
    const int bx = ((fid & 7) << 3) | ((fid >> 3) & 7);
    const int by = fid >> 6;
    const int row0 = bx * 128, col0 = by * 128;

    f32x4 acc[4][4];
#pragma unroll
    for (int i = 0; i < 4; ++i)
#pragma unroll
        for (int j = 0; j < 4; ++j) acc[i][j] = (f32x4){0.f, 0.f, 0.f, 0.f};

    const u16* Ag = A + (size_t)(row0 + (tid >> 2)) * K + ((tid & 3) * 8);
    const u16* Bg = Bm + (size_t)(col0 + (tid >> 2)) * K + ((tid & 3) * 8);
    const size_t stride64 = (size_t)64 * K;
    const int wo512 = wave * 512;

    // prologue: stage tile 0 into buffer 0
    gl_lds16(Ag, As[0] + wo512);
    gl_lds16(Ag + stride64, As[0] + 2048 + wo512);
    gl_lds16(Bg, Bs[0] + wo512);
    gl_lds16(Bg + stride64, Bs[0] + 2048 + wo512);
    __syncthreads();
    int buf = 0;

    for (int k0 = 0; k0 < K; k0 += 32) {
        if (k0 + 32 < K) {   // issue next-tile loads (drained at this iter's barrier)
            gl_lds16(Ag + k0 + 32, As[buf ^ 1] + wo512);
            gl_lds16(Ag + k0 + 32 + stride64, As[buf ^ 1] + 2048 + wo512);
            gl_lds16(Bg + k0 + 32, Bs[buf ^ 1] + wo512);
            gl_lds16(Bg + k0 + 32 + stride64, Bs[buf ^ 1] + 2048 + wo512);
        }
        const u16* Asb = As[buf];
        const u16* Bsb = Bs[buf];
        short8 af[4], bfr[4];
#pragma unroll
        for (int mi = 0; mi < 4; ++mi)
            af[mi] = *(const short8*)&Asb[(wm * 64 + mi * 16 + l16) * 32 + quad * 8];
#pragma unroll
        for (int ni = 0; ni < 4; ++ni)
            bfr[ni] = *(const short8*)&Bsb[(wn * 64 + ni * 16 + l16) * 32 + quad * 8];
#pragma unroll
        for (int mi = 0; mi < 4; ++mi)
#pragma unroll
            for (int ni = 0; ni < 4; ++ni)
                acc[mi][ni] = __builtin_amdgcn_mfma_f32_16x16x32_bf16(
                    af[mi], bfr[ni], acc[mi][ni], 0, 0, 0);
        __syncthreads();
        buf ^= 1;
    }

#pragma unroll
    for (int mi = 0; mi < 4; ++mi) {
#pragma unroll
        for (int ni = 0; ni < 4; ++ni) {
            const int r = row0 + wm * 64 + mi * 16 + quad * 4;
            const int c = col0 + wn * 64 + ni * 16 + l16;
#pragma unroll
            for (int rr = 0; rr < 4; ++rr) {
                float v = acc[mi][ni][rr];
                if constexpr (sizeof(OutT) == 2)
                    C[(size_t)(r + rr) * N + c] = (OutT)f2bf(v);
                else
                    C[(size_t)(r + rr) * N + c] = (OutT)v;
            }
        }
    }
}

// ---------------- QKV GEMM with fused V-transpose epilogue ----------------
// Same T3-minimum prefetch restructure; epilogues unchanged.
__global__ __launch_bounds__(256) void gemm_qkv(const u16* __restrict__ A,
                                                const u16* __restrict__ Bm,
                                                u16* __restrict__ Cq,
                                                u16* __restrict__ vtb) {
    const int Kd = ND, Nn = NTD;
    __shared__ __align__(16) u16 As[2][128 * 32];
    __shared__ __align__(16) u16 Bs[2][128 * 32];
    const int tid  = threadIdx.x;
    const int wave = tid >> 6, lane = tid & 63;
    const int quad = lane >> 4, l16 = lane & 15;
    const int wm = wave >> 1, wn = wave & 1;
    const int fid = blockIdx.y * gridDim.x + blockIdx.x;   // gridDim.x == 64
    const int bx = ((fid & 7) << 3) | ((fid >> 3) & 7);
    const int by = fid >> 6;
    const int row0 = bx * 128, col0 = by * 128;

    f32x4 acc[4][4];
#pragma unroll
    for (int i = 0; i < 4; ++i)
#pragma unroll
        for (int j = 0; j < 4; ++j) acc[i][j] = (f32x4){0.f, 0.f, 0.f, 0.f};

    const u16* Ag = A + (size_t)(row0 + (tid >> 2)) * Kd + ((tid & 3) * 8);
    const u16* Bg = Bm + (size_t)(col0 + (tid >> 2)) * Kd + ((tid & 3) * 8);
    const size_t stride64 = (size_t)64 * Kd;
    const int wo512 = wave * 512;

    gl_lds16(Ag, As[0] + wo512);
    gl_lds16(Ag + stride64, As[0] + 2048 + wo512);
    gl_lds16(Bg, Bs[0] + wo512);
    gl_lds16(Bg + stride64, Bs[0] + 2048 + wo512);
    __syncthreads();
    int buf = 0;

    for (int k0 = 0; k0 < Kd; k0 += 32) {
        if (k0 + 32 < Kd) {
            gl_lds16(Ag + k0 + 32, As[buf ^ 1] + wo512);
            gl_lds16(Ag + k0 + 32 + stride64, As[buf ^ 1] + 2048 + wo512);
            gl_lds16(Bg + k0 + 32, Bs[buf ^ 1] + wo512);
            gl_lds16(Bg + k0 + 32 + stride64, Bs[buf ^ 1] + 2048 + wo512);
        }
        const u16* Asb = As[buf];
        const u16* Bsb = Bs[buf];
        short8 af[4], bfr[4];
#pragma unroll
        for (int mi = 0; mi < 4; ++mi)
            af[mi] = *(const short8*)&Asb[(wm * 64 + mi * 16 + l16) * 32 + quad * 8];
#pragma unroll
        for (int ni = 0; ni < 4; ++ni)
            bfr[ni] = *(const short8*)&Bsb[(wn * 64 + ni * 16 + l16) * 32 + quad * 8];
#pragma unroll
        for (int mi = 0; mi < 4; ++mi)
#pragma unroll
            for (int ni = 0; ni < 4; ++ni)
                acc[mi][ni] = __builtin_amdgcn_mfma_f32_16x16x32_bf16(
                    af[mi], bfr[ni], acc[mi][ni], 0, 0, 0);
        __syncthreads();
        buf ^= 1;
    }

    if (col0 < 2048) {
        // Q,K: row-major into qkv
#pragma unroll
        for (int mi = 0; mi < 4; ++mi)
#pragma unroll
            for (int ni = 0; ni < 4; ++ni) {
                const int r = row0 + wm * 64 + mi * 16 + quad * 4;
                const int c = col0 + wn * 64 + ni * 16 + l16;
#pragma unroll
                for (int rr = 0; rr < 4; ++rr)
                    Cq[(size_t)(r + rr) * Nn + c] = f2bf(acc[mi][ni][rr]);
            }
    } else {
        // V: transpose 64x64 per wave -> vtb[bh][d][t]
        const int hb = ((col0 - 2048) >> 6) + wn;         // head index 0..15
        const int bq = (row0 + wm * 64) >> 11;            // batch
        const int tb = (row0 + wm * 64) & 2047;           // t base
        u16* Ovt = vtb + (size_t)(bq * NH + hb) * 64 * NT + tb;
#pragma unroll
        for (int phase = 0; phase < 2; ++phase) {
            __syncthreads();
            if ((wave >> 1) == phase) {
                u16* L = (wave & 1) ? Bs[0] : As[0];   // 4096 u16 = 64x64
#pragma unroll
                for (int mi = 0; mi < 4; ++mi) {
                    const int r4 = mi * 4 + quad;         // 4-elem r chunk idx
#pragma unroll
                    for (int ni = 0; ni < 4; ++ni) {
                        const int cl = ni * 16 + l16;     // local d
                        u32 lo = (u32)f2bf(acc[mi][ni][0]) | ((u32)f2bf(acc[mi][ni][1]) << 16);
                        u32 hi = (u32)f2bf(acc[mi][ni][2]) | ((u32)f2bf(acc[mi][ni][3]) << 16);
                        u32* p = (u32*)&L[cl * 64 + (((r4 ^ cl) & 15) << 2)];
                        p[0] = lo; p[1] = hi;
                    }
                }
#pragma unroll
                for (int rep = 0; rep < 8; ++rep) {
                    const int cl = (lane >> 3) + rep * 8; // local d row
                    const int tc = lane & 7;              // t chunk (8 u16)
                    const u32* p0 = (const u32*)&L[cl * 64 + ((((2 * tc) ^ cl) & 15) << 2)];
                    const u32* p1 = (const u32*)&L[cl * 64 + ((((2 * tc + 1) ^ cl) & 15) << 2)];
                    u32 o0 = p0[0], o1 = p0[1], o2 = p1[0], o3 = p1[1];
                    u32* q = (u32*)(Ovt + (size_t)cl * NT + tc * 8);
                    q[0] = o0; q[1] = o1; q[2] = o2; q[3] = o3;
                }
            }
        }
    }
}

// ---------------- flash prefix-LM attention (v8, unchanged) ----------------
// v5 inner loop + XCD-local LPT task queues. Queue x: 256 tasks =
// 8 bh (= [8x,8x+8), all same batch b hence same P) x 32 q-tiles,
// longest-tile-first. Blocks drain own XCD's queue (L2 locality:
// 8 bh x 0.5 MB = 4 MB = one XCD L2), then steal for correctness.
#define GETREG_XCC_ID 6164   // id=20, offset=0, size=4
__global__ __launch_bounds__(256) void flash_prefix(const u16* __restrict__ qkv,
                                                    const u16* __restrict__ vt,
                                                    const int* __restrict__ plen,
                                                    u16* __restrict__ attn,
                                                    u32* __restrict__ ctr) {
    __shared__ __align__(16) u16 Vt2[2][2048];  // [d 64][t 32] swizzled
    __shared__ __align__(16) u16 Kt2[2][2048];  // [k 32][d 64] swizzled
    __shared__ __align__(16) u16 Pl[4 * 512];   // per-wave 16x32 swizzled
    __shared__ int taskS;

    const int tid  = threadIdx.x;
    const int wave = tid >> 6, lane = tid & 63;
    const int quad = lane >> 4, l16 = lane & 15;
    const float QSCALE = 0.18033688f;           // log2(e)/8
    const int ldsoff = wave * 512;

    short8 ones;
#pragma unroll
    for (int j = 0; j < 8; ++j) ones[j] = (short)0x3F80;

    const bool is64 = (plen[1] == 0) && (plen[3] == 0);
    const int xcd = (int)(__builtin_amdgcn_s_getreg(GETREG_XCC_ID) & 7);
    int q = xcd;

    for (;;) {
        if (tid == 0) taskS = (int)atomicAdd(ctr + q * 16, 1u);
        __syncthreads();            // broadcast + prev-task LDS reads done
        const int pos = taskS;
        if (pos >= 256) {           // queue q drained; steal or finish
            q = (q + 1) & 7;
            if (q == xcd) break;
            continue;
        }

        const int bh = (q << 3) | (pos & 7);
        const int b = bh >> 4, h = bh & 15;
        const int q0 = (31 - (pos >> 3)) * 64;   // LPT: longest tiles first

        int P = is64 ? plen[2 * b] : plen[b];
        P = P < 0 ? 0 : (P > NT ? NT : P);

        const u16* Qg = qkv + (size_t)b * NT * NTD + h * NDK;
        const u16* Kg = Qg + ND;
        const u16* Vtb = vt + (size_t)bh * 64 * NT;   // [d][t]
        const int qbase = q0 + wave * 16;
        u16* Pw = Pl + wave * 512;

        // DMA lane->source mapping (swizzle baked into global address)
        const int vrow = tid >> 2;
        const int vtq = (tid ^ (vrow >> 1) ^ (vrow >> 3)) & 3;
        const u16* vsrc = Vtb + (size_t)vrow * NT + vtq * 8;
        const int krow = tid >> 3;
        const int kc = (tid ^ krow) & 7;
        const u16* ksrc = Kg + (size_t)krow * NTD + kc * 8;

        // Q fragments pre-scaled into exp2 domain
        short8 qa[2];
#pragma unroll
        for (int kd = 0; kd < 2; ++kd) {
            short8 tq = *(const short8*)(Qg + (size_t)(qbase + l16) * NTD + kd * 32 + quad * 8);
#pragma unroll
            for (int j = 0; j < 8; ++j)
                tq[j] = (short)f2bf(bf2f((u16)tq[j]) * QSCALE);
            qa[kd] = tq;
        }

        f32x4 o[4];
#pragma unroll
        for (int nt = 0; nt < 4; ++nt) o[nt] = (f32x4){0.f, 0.f, 0.f, 0.f};
        f32x4 lsum = (f32x4){0.f, 0.f, 0.f, 0.f};

        int kl[4];
#pragma unroll
        for (int rr = 0; rr < 4; ++rr) {
            const int qrow = qbase + quad * 4 + rr;
            kl[rr] = (qrow < P) ? P : (qrow + 1);
        }
        const int klmin = (qbase < P) ? P : (qbase + 1);  // wave-uniform
        const int kmax = (q0 + 64 > P) ? (q0 + 64) : P;   // block-uniform

        gl_lds16(vsrc, &Vt2[0][ldsoff]);
        gl_lds16(ksrc, &Kt2[0][ldsoff]);
        int buf = 0;

        for (int k0 = 0; k0 < kmax; k0 += 32) {
            __syncthreads();
            if (k0 + 32 < kmax) {
                gl_lds16(vsrc + (k0 + 32), &Vt2[buf ^ 1][ldsoff]);
                gl_lds16(ksrc + (size_t)(k0 + 32) * NTD, &Kt2[buf ^ 1][ldsoff]);
            }
            const u16* Kb = Kt2[buf];
            const u16* Vb = Vt2[buf];

            f32x4 s[2];
#pragma unroll
            for (int ni = 0; ni < 2; ++ni) {
                s[ni] = (f32x4){0.f, 0.f, 0.f, 0.f};
#pragma unroll
                for (int kd = 0; kd < 2; ++kd) {
                    const int r = ni * 16 + l16;
                    const short8 kb = *(const short8*)&Kb[r * 64 + ((((kd * 4 + quad) ^ r) & 7) << 3)];
                    s[ni] = __builtin_amdgcn_mfma_f32_16x16x32_bf16(qa[kd], kb, s[ni], 0, 0, 0);
                }
            }

            const bool full = (k0 + 32 <= klmin);
#pragma unroll
            for (int ni = 0; ni < 2; ++ni) {
#pragma unroll
                for (int rr = 0; rr < 4; ++rr) {
                    float sv = s[ni][rr];
                    if (!full) {
                        const int kpos = k0 + ni * 16 + l16;
                        sv = (kpos < kl[rr]) ? sv : -1e30f;
                    }
                    const float p = exp2f(sv);
                    const u32 u = __builtin_bit_cast(u32, p) + 0x8000u;
                    Pw[swz(quad * 4 + rr, ni * 16 + l16)] = (u16)(u >> 16);
                }
            }

            const short8 pa = *(const short8*)&Pw[swz(l16, quad * 8)];
            lsum = __builtin_amdgcn_mfma_f32_16x16x32_bf16(pa, ones, lsum, 0, 0, 0);
#pragma unroll
            for (int nt = 0; nt < 4; ++nt) {
                const short8 vb = *(const short8*)&Vb[swz(nt * 16 + l16, quad * 8)];
                o[nt] = __builtin_amdgcn_mfma_f32_16x16x32_bf16(pa, vb, o[nt], 0, 0, 0);
            }
            buf ^= 1;
        }

        // epilogue (no shuffles: lsum shares o's C-layout)
#pragma unroll
        for (int rr = 0; rr < 4; ++rr) {
            const float inv = 1.0f / lsum[rr];
            const size_t rowoff = (size_t)(b * NT + qbase + quad * 4 + rr) * ND + h * NDK;
#pragma unroll
            for (int nt = 0; nt < 4; ++nt)
                attn[rowoff + nt * 16 + l16] = f2bf(o[nt][rr] * inv);
        }
    }
}

extern "C" void kernel_launch(void* const* d_in, const int* in_sizes, int n_in,
                              void* d_out, int out_size, void* d_ws, size_t ws_size,
                              hipStream_t stream) {
    const float* x    = (const float*)d_in[0];
    const int*   plen = (const int*)d_in[1];
    const float* wqkv = (const float*)d_in[2];
    const float* wo   = (const float*)d_in[3];
    float* out = (float*)d_out;

    char* ws = (char*)d_ws;
    u16* xb   = (u16*)(ws);                  // 16,777,216
    u16* wqb  = (u16*)(ws + 16777216);       //  6,291,456
    u16* wob  = (u16*)(ws + 23068672);       //  2,097,152
    u16* qkv  = (u16*)(ws + 25165824);       // 50,331,648 (V cols unused)
    u16* attn = (u16*)(ws + 75497472);       // 16,777,216
    u16* vtb  = (u16*)(ws + 92274688);       // 33,554,432
    u32* ctr  = (u32*)(ws + 75496960);       // 512 B inside unused qkv V-section

    hipMemsetAsync(ctr, 0, 512, stream);

    // fused conversions: x, W_qkv, W_o
    cvt_all<<<6144, 256, 0, stream>>>(x, wqkv, wo, xb, wqb, wob);

    // QKV GEMM; V columns go directly to vtb[bh][d][t]
    gemm_qkv<<<dim3(64, 24), 256, 0, stream>>>(xb, wqb, qkv, vtb);

    // attention (XCD-local LPT task queues)
    flash_prefix<<<1024, 256, 0, stream>>>(qkv, vtb, plen, attn, ctr);

    // out = attn @ W_o^T  (M=8192, N=1024, K=1024)
    gemm_bt<float><<<dim3(64, 8), 256, 0, stream>>>(attn, wob, out, NB * NT, ND, ND);
}

// Round 5
// 292.044 us; speedup vs baseline: 1.0597x; 1.0597x over previous
//
#include <hip/hip_runtime.h>
#include <stdint.h>

#define NB 4
#define NT 2048
#define ND 1024
#define NH 16
#define NDK 64
#define NTD 3072   // 3*ND

typedef __attribute__((ext_vector_type(8))) short short8;
typedef __attribute__((ext_vector_type(4))) float f32x4;
typedef unsigned short u16;
typedef unsigned int u32;

__device__ __forceinline__ u16 f2bf(float f) {
    u32 u = __builtin_bit_cast(u32, f);
    u += 0x7fffu + ((u >> 16) & 1u);   // RNE
    return (u16)(u >> 16);
}
__device__ __forceinline__ float bf2f(u16 s) {
    u32 u = ((u32)s) << 16;
    return __builtin_bit_cast(float, u);
}

__device__ __forceinline__ void gl_lds16(const u16* g, u16* l) {
    __builtin_amdgcn_global_load_lds(
        (const __attribute__((address_space(1))) u32*)g,
        (__attribute__((address_space(3))) u32*)l, 16, 0, 0);
}

// XOR-swizzled tile index (rows of 32 u16 / 64B, 4 atoms of 8 u16).
__device__ __forceinline__ int swz(int row, int col) {
    return row * 32 + ((((col >> 3) ^ (row >> 1) ^ (row >> 3)) & 3) << 3) + (col & 7);
}

// ---------------- fused fp32 -> bf16 (RNE) for x, W_qkv, W_o ----------------
__global__ __launch_bounds__(256) void cvt_all(const float* __restrict__ x,
                                               const float* __restrict__ wqkv,
                                               const float* __restrict__ wo,
                                               u16* __restrict__ xb,
                                               u16* __restrict__ wqb,
                                               u16* __restrict__ wob) {
    const int n0 = NB * NT * ND;       // 8388608
    const int n1 = 3 * ND * ND;        // 3145728
    int i = (blockIdx.x * 256 + threadIdx.x) * 8;
    const float* src;
    u16* dst;
    if (i < n0) {
        src = x + i; dst = xb + i;
    } else if (i < n0 + n1) {
        src = wqkv + (i - n0); dst = wqb + (i - n0);
    } else {
        src = wo + (i - n0 - n1); dst = wob + (i - n0 - n1);
    }
    float4 a = *(const float4*)(src);
    float4 b = *(const float4*)(src + 4);
    short8 r;
    r[0] = (short)f2bf(a.x); r[1] = (short)f2bf(a.y);
    r[2] = (short)f2bf(a.z); r[3] = (short)f2bf(a.w);
    r[4] = (short)f2bf(b.x); r[5] = (short)f2bf(b.y);
    r[6] = (short)f2bf(b.z); r[7] = (short)f2bf(b.w);
    *(short8*)(dst) = r;
}

// ---------------- bf16 GEMM: C[M,N] = A[M,K] * Bm[N,K]^T (Round-3 form) ----
template <typename OutT>
__global__ __launch_bounds__(256) void gemm_bt(const u16* __restrict__ A,
                                               const u16* __restrict__ Bm,
                                               OutT* __restrict__ C,
                                               int M, int N, int K) {
    __shared__ __align__(16) u16 As[128 * 32];
    __shared__ __align__(16) u16 Bs[128 * 32];
    const int tid  = threadIdx.x;
    const int wave = tid >> 6, lane = tid & 63;
    const int quad = lane >> 4, l16 = lane & 15;
    const int wm = wave >> 1, wn = wave & 1;
    const int fid = blockIdx.y * gridDim.x + blockIdx.x;   // gridDim.x == 64
    const int bx = ((fid & 7) << 3) | ((fid >> 3) & 7);
    const int by = fid >> 6;
    const int row0 = bx * 128, col0 = by * 128;

    f32x4 acc[4][4];
#pragma unroll
    for (int i = 0; i < 4; ++i)
#pragma unroll
        for (int j = 0; j < 4; ++j) acc[i][j] = (f32x4){0.f, 0.f, 0.f, 0.f};

    const u16* Ag = A + (size_t)(row0 + (tid >> 2)) * K + ((tid & 3) * 8);
    const u16* Bg = Bm + (size_t)(col0 + (tid >> 2)) * K + ((tid & 3) * 8);
    const size_t stride64 = (size_t)64 * K;
    u16* As0 = As + wave * 512;
    u16* As1 = As + 2048 + wave * 512;
    u16* Bs0 = Bs + wave * 512;
    u16* Bs1 = Bs + 2048 + wave * 512;

    for (int k0 = 0; k0 < K; k0 += 32) {
        gl_lds16(Ag + k0, As0);
        gl_lds16(Ag + k0 + stride64, As1);
        gl_lds16(Bg + k0, Bs0);
        gl_lds16(Bg + k0 + stride64, Bs1);
        __syncthreads();
        short8 af[4], bfr[4];
#pragma unroll
        for (int mi = 0; mi < 4; ++mi)
            af[mi] = *(const short8*)&As[(wm * 64 + mi * 16 + l16) * 32 + quad * 8];
#pragma unroll
        for (int ni = 0; ni < 4; ++ni)
            bfr[ni] = *(const short8*)&Bs[(wn * 64 + ni * 16 + l16) * 32 + quad * 8];
#pragma unroll
        for (int mi = 0; mi < 4; ++mi)
#pragma unroll
            for (int ni = 0; ni < 4; ++ni)
                acc[mi][ni] = __builtin_amdgcn_mfma_f32_16x16x32_bf16(
                    af[mi], bfr[ni], acc[mi][ni], 0, 0, 0);
        __syncthreads();
    }

#pragma unroll
    for (int mi = 0; mi < 4; ++mi) {
#pragma unroll
        for (int ni = 0; ni < 4; ++ni) {
            const int r = row0 + wm * 64 + mi * 16 + quad * 4;
            const int c = col0 + wn * 64 + ni * 16 + l16;
#pragma unroll
            for (int rr = 0; rr < 4; ++rr) {
                float v = acc[mi][ni][rr];
                if constexpr (sizeof(OutT) == 2)
                    C[(size_t)(r + rr) * N + c] = (OutT)f2bf(v);
                else
                    C[(size_t)(r + rr) * N + c] = (OutT)v;
            }
        }
    }
}

// ---------------- Q/K GEMM: 256x256 tile, BK=32, double-buffered ----------
// 8 waves (2x4), per-wave 128x64 output, acc[8][4]. LDS 64KB (2x16KB per op).
// Tiles stored 2-rows-per-128B super-row with XOR slot swizzle
// (slot ^= srow&7): ds_read_b128 frag reads land 2 lanes/bank (free).
// Swizzle baked into the GLOBAL source address of global_load_lds (linear
// LDS dest, rule #21). Stage of tile t+1 issued at top of tile t, drained
// by the end-of-tile __syncthreads (~32 MFMA + 12 ds_read of cover).
__global__ __launch_bounds__(512, 2) void gemm_qk256(const u16* __restrict__ A,
                                                     const u16* __restrict__ Bm,
                                                     u16* __restrict__ Cq) {
    __shared__ __align__(16) u16 rbA[2][8192];
    __shared__ __align__(16) u16 rbB[2][8192];
    u16* const rbAf = &rbA[0][0];
    u16* const rbBf = &rbB[0][0];
    const int tid  = threadIdx.x;
    const int wave = tid >> 6, lane = tid & 63;
    const int quad = lane >> 4, l16 = lane & 15;
    const int wm = wave >> 2, wn = wave & 3;          // 2 x 4 wave grid
    const int K = ND;                                  // 1024
    // fid remap: XCD x (fid&7) owns bx in [4x,4x+4) -> contiguous A slab.
    const int fid = blockIdx.x;                        // 256 blocks = 1/CU
    const int bx = (fid & 7) * 4 + (fid >> 6);
    const int by = (fid >> 3) & 7;
    const int row0 = bx * 256, col0 = by * 256;

    // staging source mapping: call c covers atoms a = c*512+tid (16B each);
    // atom a -> srow=a>>3, slot=(a&7)^(srow&7), row=2*srow+(slot>>2), k8=slot&3
    const int sr0 = tid >> 3, sl0 = (tid & 7) ^ (sr0 & 7);
    const int a1 = 512 + tid;
    const int sr1 = a1 >> 3, sl1 = (a1 & 7) ^ (sr1 & 7);
    const int r0i = 2 * sr0 + (sl0 >> 2), k0i = (sl0 & 3) * 8;
    const int r1i = 2 * sr1 + (sl1 >> 2), k1i = (sl1 & 3) * 8;
    const u16* srcA0 = A + (size_t)(row0 + r0i) * K + k0i;
    const u16* srcA1 = A + (size_t)(row0 + r1i) * K + k1i;
    const u16* srcB0 = Bm + (size_t)(col0 + r0i) * K + k0i;
    const u16* srcB1 = Bm + (size_t)(col0 + r1i) * K + k1i;
    const int ldsc0 = wave * 512;          // call-0 per-wave dest (u16)
    const int ldsc1 = 4096 + wave * 512;   // call-1

    // frag read offsets (u16 within one 8192-u16 tile), per-lane constant
    int aoff[8], boff[4];
#pragma unroll
    for (int mi = 0; mi < 8; ++mi) {
        const int row = wm * 128 + mi * 16 + l16;
        const int srow = row >> 1;
        const int slot = ((((row & 1) << 2) | quad) ^ (srow & 7));
        aoff[mi] = srow * 64 + slot * 8;
    }
#pragma unroll
    for (int ni = 0; ni < 4; ++ni) {
        const int row = wn * 64 + ni * 16 + l16;
        const int srow = row >> 1;
        const int slot = ((((row & 1) << 2) | quad) ^ (srow & 7));
        boff[ni] = srow * 64 + slot * 8;
    }

    f32x4 acc[8][4];
#pragma unroll
    for (int i = 0; i < 8; ++i)
#pragma unroll
        for (int j = 0; j < 4; ++j) acc[i][j] = (f32x4){0.f, 0.f, 0.f, 0.f};

    // prologue: stage tile 0 into buffer 0
    gl_lds16(srcA0, rbAf + ldsc0);
    gl_lds16(srcA1, rbAf + ldsc1);
    gl_lds16(srcB0, rbBf + ldsc0);
    gl_lds16(srcB1, rbBf + ldsc1);
    __syncthreads();

#define QK_TILE(T, TB, NB_)                                                    \
    {                                                                          \
        if ((T) + 1 < 32) {                                                    \
            const int ko = ((T) + 1) * 32;                                     \
            gl_lds16(srcA0 + ko, rbAf + (NB_) + ldsc0);                        \
            gl_lds16(srcA1 + ko, rbAf + (NB_) + ldsc1);                        \
            gl_lds16(srcB0 + ko, rbBf + (NB_) + ldsc0);                        \
            gl_lds16(srcB1 + ko, rbBf + (NB_) + ldsc1);                        \
        }                                                                      \
        short8 af[4], bfr[4];                                                  \
        _Pragma("unroll") for (int mi = 0; mi < 4; ++mi)                       \
            af[mi] = *(const short8*)&rbAf[(TB) + aoff[mi]];                   \
        _Pragma("unroll") for (int ni = 0; ni < 4; ++ni)                       \
            bfr[ni] = *(const short8*)&rbBf[(TB) + boff[ni]];                  \
        __builtin_amdgcn_s_setprio(1);                                         \
        _Pragma("unroll") for (int mi = 0; mi < 4; ++mi)                       \
            _Pragma("unroll") for (int ni = 0; ni < 4; ++ni)                   \
                acc[mi][ni] = __builtin_amdgcn_mfma_f32_16x16x32_bf16(         \
                    af[mi], bfr[ni], acc[mi][ni], 0, 0, 0);                    \
        __builtin_amdgcn_s_setprio(0);                                         \
        __builtin_amdgcn_s_barrier();                                          \
        short8 af2[4];                                                         \
        _Pragma("unroll") for (int mi = 0; mi < 4; ++mi)                       \
            af2[mi] = *(const short8*)&rbAf[(TB) + aoff[4 + mi]];              \
        __builtin_amdgcn_s_setprio(1);                                         \
        _Pragma("unroll") for (int mi = 0; mi < 4; ++mi)                       \
            _Pragma("unroll") for (int ni = 0; ni < 4; ++ni)                   \
                acc[4 + mi][ni] = __builtin_amdgcn_mfma_f32_16x16x32_bf16(     \
                    af2[mi], bfr[ni], acc[4 + mi][ni], 0, 0, 0);               \
        __builtin_amdgcn_s_setprio(0);                                         \
        __syncthreads();                                                       \
    }

    for (int t2 = 0; t2 < 32; t2 += 2) {
        QK_TILE(t2, 0, 8192);
        QK_TILE(t2 + 1, 8192, 0);
    }
#undef QK_TILE

    // epilogue: row-major bf16 into qkv (cols < 2048 only by construction)
#pragma unroll
    for (int mi = 0; mi < 8; ++mi) {
#pragma unroll
        for (int ni = 0; ni < 4; ++ni) {
            const int r = row0 + wm * 128 + mi * 16 + quad * 4;
            const int c = col0 + wn * 64 + ni * 16 + l16;
#pragma unroll
            for (int rr = 0; rr < 4; ++rr)
                Cq[(size_t)(r + rr) * NTD + c] = f2bf(acc[mi][ni][rr]);
        }
    }
}

// ---------------- V GEMM (128x128, Round-3 loop) + transpose epilogue ------
__global__ __launch_bounds__(256) void gemm_v(const u16* __restrict__ A,
                                              const u16* __restrict__ Bm,
                                              u16* __restrict__ vtb) {
    const int Kd = ND;
    __shared__ __align__(16) u16 As[128 * 32];
    __shared__ __align__(16) u16 Bs[128 * 32];
    const int tid  = threadIdx.x;
    const int wave = tid >> 6, lane = tid & 63;
    const int quad = lane >> 4, l16 = lane & 15;
    const int wm = wave >> 1, wn = wave & 1;
    const int fid = blockIdx.y * gridDim.x + blockIdx.x;   // gridDim.x == 64
    const int bx = ((fid & 7) << 3) | ((fid >> 3) & 7);
    const int by = fid >> 6;
    const int row0 = bx * 128, col0 = 2048 + by * 128;     // V columns only

    f32x4 acc[4][4];
#pragma unroll
    for (int i = 0; i < 4; ++i)
#pragma unroll
        for (int j = 0; j < 4; ++j) acc[i][j] = (f32x4){0.f, 0.f, 0.f, 0.f};

    const u16* Ag = A + (size_t)(row0 + (tid >> 2)) * Kd + ((tid & 3) * 8);
    const u16* Bg = Bm + (size_t)(col0 + (tid >> 2)) * Kd + ((tid & 3) * 8);
    const size_t stride64 = (size_t)64 * Kd;
    u16* As0 = As + wave * 512;
    u16* As1 = As + 2048 + wave * 512;
    u16* Bs0 = Bs + wave * 512;
    u16* Bs1 = Bs + 2048 + wave * 512;

    for (int k0 = 0; k0 < Kd; k0 += 32) {
        gl_lds16(Ag + k0, As0);
        gl_lds16(Ag + k0 + stride64, As1);
        gl_lds16(Bg + k0, Bs0);
        gl_lds16(Bg + k0 + stride64, Bs1);
        __syncthreads();
        short8 af[4], bfr[4];
#pragma unroll
        for (int mi = 0; mi < 4; ++mi)
            af[mi] = *(const short8*)&As[(wm * 64 + mi * 16 + l16) * 32 + quad * 8];
#pragma unroll
        for (int ni = 0; ni < 4; ++ni)
            bfr[ni] = *(const short8*)&Bs[(wn * 64 + ni * 16 + l16) * 32 + quad * 8];
#pragma unroll
        for (int mi = 0; mi < 4; ++mi)
#pragma unroll
            for (int ni = 0; ni < 4; ++ni)
                acc[mi][ni] = __builtin_amdgcn_mfma_f32_16x16x32_bf16(
                    af[mi], bfr[ni], acc[mi][ni], 0, 0, 0);
        __syncthreads();
    }

    // V: transpose 64x64 per wave -> vtb[bh][d][t] (proven Round-3 code)
    const int hb = ((col0 - 2048) >> 6) + wn;         // head index 0..15
    const int bq = (row0 + wm * 64) >> 11;            // batch
    const int tb = (row0 + wm * 64) & 2047;           // t base
    u16* Ovt = vtb + (size_t)(bq * NH + hb) * 64 * NT + tb;
#pragma unroll
    for (int phase = 0; phase < 2; ++phase) {
        __syncthreads();
        if ((wave >> 1) == phase) {
            u16* L = (wave & 1) ? Bs : As;   // 4096 u16 = 64x64
#pragma unroll
            for (int mi = 0; mi < 4; ++mi) {
                const int r4 = mi * 4 + quad;         // 4-elem r chunk idx
#pragma unroll
                for (int ni = 0; ni < 4; ++ni) {
                    const int cl = ni * 16 + l16;     // local d
                    u32 lo = (u32)f2bf(acc[mi][ni][0]) | ((u32)f2bf(acc[mi][ni][1]) << 16);
                    u32 hi = (u32)f2bf(acc[mi][ni][2]) | ((u32)f2bf(acc[mi][ni][3]) << 16);
                    u32* p = (u32*)&L[cl * 64 + (((r4 ^ cl) & 15) << 2)];
                    p[0] = lo; p[1] = hi;
                }
            }
#pragma unroll
            for (int rep = 0; rep < 8; ++rep) {
                const int cl = (lane >> 3) + rep * 8; // local d row
                const int tc = lane & 7;              // t chunk (8 u16)
                const u32* p0 = (const u32*)&L[cl * 64 + ((((2 * tc) ^ cl) & 15) << 2)];
                const u32* p1 = (const u32*)&L[cl * 64 + ((((2 * tc + 1) ^ cl) & 15) << 2)];
                u32 o0 = p0[0], o1 = p0[1], o2 = p1[0], o3 = p1[1];
                u32* q = (u32*)(Ovt + (size_t)cl * NT + tc * 8);
                q[0] = o0; q[1] = o1; q[2] = o2; q[3] = o3;
            }
        }
    }
}

// ---------------- flash prefix-LM attention (v8, unchanged) ----------------
#define GETREG_XCC_ID 6164   // id=20, offset=0, size=4
__global__ __launch_bounds__(256) void flash_prefix(const u16* __restrict__ qkv,
                                                    const u16* __restrict__ vt,
                                                    const int* __restrict__ plen,
                                                    u16* __restrict__ attn,
                                                    u32* __restrict__ ctr) {
    __shared__ __align__(16) u16 Vt2[2][2048];  // [d 64][t 32] swizzled
    __shared__ __align__(16) u16 Kt2[2][2048];  // [k 32][d 64] swizzled
    __shared__ __align__(16) u16 Pl[4 * 512];   // per-wave 16x32 swizzled
    __shared__ int taskS;

    const int tid  = threadIdx.x;
    const int wave = tid >> 6, lane = tid & 63;
    const int quad = lane >> 4, l16 = lane & 15;
    const float QSCALE = 0.18033688f;           // log2(e)/8
    const int ldsoff = wave * 512;

    short8 ones;
#pragma unroll
    for (int j = 0; j < 8; ++j) ones[j] = (short)0x3F80;

    const bool is64 = (plen[1] == 0) && (plen[3] == 0);
    const int xcd = (int)(__builtin_amdgcn_s_getreg(GETREG_XCC_ID) & 7);
    int q = xcd;

    for (;;) {
        if (tid == 0) taskS = (int)atomicAdd(ctr + q * 16, 1u);
        __syncthreads();            // broadcast + prev-task LDS reads done
        const int pos = taskS;
        if (pos >= 256) {           // queue q drained; steal or finish
            q = (q + 1) & 7;
            if (q == xcd) break;
            continue;
        }

        const int bh = (q << 3) | (pos & 7);
        const int b = bh >> 4, h = bh & 15;
        const int q0 = (31 - (pos >> 3)) * 64;   // LPT: longest tiles first

        int P = is64 ? plen[2 * b] : plen[b];
        P = P < 0 ? 0 : (P > NT ? NT : P);

        const u16* Qg = qkv + (size_t)b * NT * NTD + h * NDK;
        const u16* Kg = Qg + ND;
        const u16* Vtb = vt + (size_t)bh * 64 * NT;   // [d][t]
        const int qbase = q0 + wave * 16;
        u16* Pw = Pl + wave * 512;

        // DMA lane->source mapping (swizzle baked into global address)
        const int vrow = tid >> 2;
        const int vtq = (tid ^ (vrow >> 1) ^ (vrow >> 3)) & 3;
        const u16* vsrc = Vtb + (size_t)vrow * NT + vtq * 8;
        const int krow = tid >> 3;
        const int kc = (tid ^ krow) & 7;
        const u16* ksrc = Kg + (size_t)krow * NTD + kc * 8;

        // Q fragments pre-scaled into exp2 domain
        short8 qa[2];
#pragma unroll
        for (int kd = 0; kd < 2; ++kd) {
            short8 tq = *(const short8*)(Qg + (size_t)(qbase + l16) * NTD + kd * 32 + quad * 8);
#pragma unroll
            for (int j = 0; j < 8; ++j)
                tq[j] = (short)f2bf(bf2f((u16)tq[j]) * QSCALE);
            qa[kd] = tq;
        }

        f32x4 o[4];
#pragma unroll
        for (int nt = 0; nt < 4; ++nt) o[nt] = (f32x4){0.f, 0.f, 0.f, 0.f};
        f32x4 lsum = (f32x4){0.f, 0.f, 0.f, 0.f};

        int kl[4];
#pragma unroll
        for (int rr = 0; rr < 4; ++rr) {
            const int qrow = qbase + quad * 4 + rr;
            kl[rr] = (qrow < P) ? P : (qrow + 1);
        }
        const int klmin = (qbase < P) ? P : (qbase + 1);  // wave-uniform
        const int kmax = (q0 + 64 > P) ? (q0 + 64) : P;   // block-uniform

        gl_lds16(vsrc, &Vt2[0][ldsoff]);
        gl_lds16(ksrc, &Kt2[0][ldsoff]);
        int buf = 0;

        for (int k0 = 0; k0 < kmax; k0 += 32) {
            __syncthreads();
            if (k0 + 32 < kmax) {
                gl_lds16(vsrc + (k0 + 32), &Vt2[buf ^ 1][ldsoff]);
                gl_lds16(ksrc + (size_t)(k0 + 32) * NTD, &Kt2[buf ^ 1][ldsoff]);
            }
            const u16* Kb = Kt2[buf];
            const u16* Vb = Vt2[buf];

            f32x4 s[2];
#pragma unroll
            for (int ni = 0; ni < 2; ++ni) {
                s[ni] = (f32x4){0.f, 0.f, 0.f, 0.f};
#pragma unroll
                for (int kd = 0; kd < 2; ++kd) {
                    const int r = ni * 16 + l16;
                    const short8 kb = *(const short8*)&Kb[r * 64 + ((((kd * 4 + quad) ^ r) & 7) << 3)];
                    s[ni] = __builtin_amdgcn_mfma_f32_16x16x32_bf16(qa[kd], kb, s[ni], 0, 0, 0);
                }
            }

            const bool full = (k0 + 32 <= klmin);
#pragma unroll
            for (int ni = 0; ni < 2; ++ni) {
#pragma unroll
                for (int rr = 0; rr < 4; ++rr) {
                    float sv = s[ni][rr];
                    if (!full) {
                        const int kpos = k0 + ni * 16 + l16;
                        sv = (kpos < kl[rr]) ? sv : -1e30f;
                    }
                    const float p = exp2f(sv);
                    const u32 u = __builtin_bit_cast(u32, p) + 0x8000u;
                    Pw[swz(quad * 4 + rr, ni * 16 + l16)] = (u16)(u >> 16);
                }
            }

            const short8 pa = *(const short8*)&Pw[swz(l16, quad * 8)];
            lsum = __builtin_amdgcn_mfma_f32_16x16x32_bf16(pa, ones, lsum, 0, 0, 0);
#pragma unroll
            for (int nt = 0; nt < 4; ++nt) {
                const short8 vb = *(const short8*)&Vb[swz(nt * 16 + l16, quad * 8)];
                o[nt] = __builtin_amdgcn_mfma_f32_16x16x32_bf16(pa, vb, o[nt], 0, 0, 0);
            }
            buf ^= 1;
        }

        // epilogue (no shuffles: lsum shares o's C-layout)
#pragma unroll
        for (int rr = 0; rr < 4; ++rr) {
            const float inv = 1.0f / lsum[rr];
            const size_t rowoff = (size_t)(b * NT + qbase + quad * 4 + rr) * ND + h * NDK;
#pragma unroll
            for (int nt = 0; nt < 4; ++nt)
                attn[rowoff + nt * 16 + l16] = f2bf(o[nt][rr] * inv);
        }
    }
}

extern "C" void kernel_launch(void* const* d_in, const int* in_sizes, int n_in,
                              void* d_out, int out_size, void* d_ws, size_t ws_size,
                              hipStream_t stream) {
    const float* x    = (const float*)d_in[0];
    const int*   plen = (const int*)d_in[1];
    const float* wqkv = (const float*)d_in[2];
    const float* wo   = (const float*)d_in[3];
    float* out = (float*)d_out;

    char* ws = (char*)d_ws;
    u16* xb   = (u16*)(ws);                  // 16,777,216
    u16* wqb  = (u16*)(ws + 16777216);       //  6,291,456
    u16* wob  = (u16*)(ws + 23068672);       //  2,097,152
    u16* qkv  = (u16*)(ws + 25165824);       // 50,331,648 (V cols unused)
    u16* attn = (u16*)(ws + 75497472);       // 16,777,216
    u16* vtb  = (u16*)(ws + 92274688);       // 33,554,432
    u32* ctr  = (u32*)(ws + 75496960);       // 512 B inside unused qkv V-section

    hipMemsetAsync(ctr, 0, 512, stream);

    // fused conversions: x, W_qkv, W_o
    cvt_all<<<6144, 256, 0, stream>>>(x, wqkv, wo, xb, wqb, wob);

    // Q,K GEMM: 256^2 tile, one block per CU
    gemm_qk256<<<256, 512, 0, stream>>>(xb, wqb, qkv);

    // V GEMM (+ transpose into vtb[bh][d][t])
    gemm_v<<<dim3(64, 8), 256, 0, stream>>>(xb, wqb, vtb);

    // attention (XCD-local LPT task queues)
    flash_prefix<<<1024, 256, 0, stream>>>(qkv, vtb, plen, attn, ctr);

    // out = attn @ W_o^T  (M=8192, N=1024, K=1024)
    gemm_bt<float><<<dim3(64, 8), 256, 0, stream>>>(attn, wob, out, NB * NT, ND, ND);
}